// Round 1
// baseline (2333.165 us; speedup 1.0000x reference)
//
#include <hip/hip_runtime.h>
#include <math.h>

#define FH 38
#define FW 50
#define NPIX 1900   // 38*50
#define NROIS 512

// ---------------------------------------------------------------------------
// Conv as split-K GEMM with on-the-fly im2col.
//   C[o,p] = sum_k W[o*K + k] * X[c(k)*1900 + shift(p, r(k))],  K = Kc*15,
//   k = c*15 + r.  vertical: row shift by r-7 (15x1 taps); else col shift.
// Writes fp32 partials P[split][Mpad][1900]; reduce kernel sums + bias.
// Block 16x16 threads, 64x64 output tile, 4x4 per thread, TK=16.
// ---------------------------------------------------------------------------
__global__ __launch_bounds__(256) void conv_gemm(
    const float* __restrict__ Wt, const float* __restrict__ X,
    float* __restrict__ P, int M, int Kc, int Mpad, int vertical)
{
    const int K  = Kc * 15;
    const int Ks = K / gridDim.z;          // split span, always divisible by 16
    const int k0 = blockIdx.z * Ks;
    const int tx = threadIdx.x, ty = threadIdx.y;
    const int tid = ty * 16 + tx;
    const int obase = blockIdx.y * 64;
    const int pbase = blockIdx.x * 64;

    __shared__ float As[64][17];   // [oo][kk], +1 pad
    __shared__ float Bs[16][64];   // [kk][pp]

    // A-load assignment: 64 rows x 16 k, 4 consecutive k per thread
    const int a_oo = tid >> 2;
    const int a_kq = (tid & 3) << 2;
    const float* Arow = Wt + (size_t)(obase + a_oo) * K;
    const bool a_ok = (obase + a_oo) < M;

    // B-load assignment: 16 k-rows x 64 p, 4 consecutive p per thread
    const int b_kk = tid >> 4;
    const int b_pq = (tid & 15) << 2;
    int py[4], px[4];
    bool pok[4];
#pragma unroll
    for (int j = 0; j < 4; ++j) {
        int p = pbase + b_pq + j;
        pok[j] = p < NPIX;
        int y = p / FW;
        py[j] = y; px[j] = p - y * FW;
    }

    float acc[4][4];
#pragma unroll
    for (int i = 0; i < 4; ++i)
#pragma unroll
        for (int j = 0; j < 4; ++j) acc[i][j] = 0.f;

    for (int kt = k0; kt < k0 + Ks; kt += 16) {
#pragma unroll
        for (int i = 0; i < 4; ++i)
            As[a_oo][a_kq + i] = a_ok ? Arow[kt + a_kq + i] : 0.f;
        {
            int kg = kt + b_kk;
            int c  = kg / 15;
            int r  = kg - c * 15;
            const float* Xc = X + (size_t)c * NPIX;
#pragma unroll
            for (int j = 0; j < 4; ++j) {
                float v = 0.f;
                if (pok[j]) {
                    if (vertical) {
                        int yy = py[j] + r - 7;
                        if (yy >= 0 && yy < FH) v = Xc[yy * FW + px[j]];
                    } else {
                        int xx = px[j] + r - 7;
                        if (xx >= 0 && xx < FW) v = Xc[py[j] * FW + xx];
                    }
                }
                Bs[b_kk][b_pq + j] = v;
            }
        }
        __syncthreads();
#pragma unroll
        for (int kk = 0; kk < 16; ++kk) {
            float a[4], b[4];
#pragma unroll
            for (int i = 0; i < 4; ++i) a[i] = As[ty * 4 + i][kk];
#pragma unroll
            for (int j = 0; j < 4; ++j) b[j] = Bs[kk][tx * 4 + j];
#pragma unroll
            for (int i = 0; i < 4; ++i)
#pragma unroll
                for (int j = 0; j < 4; ++j) acc[i][j] += a[i] * b[j];
        }
        __syncthreads();
    }

    float* Pp = P + (size_t)blockIdx.z * Mpad * NPIX;
#pragma unroll
    for (int i = 0; i < 4; ++i) {
        int o = obase + ty * 4 + i;
#pragma unroll
        for (int j = 0; j < 4; ++j) {
            int p = pbase + tx * 4 + j;
            if (p < NPIX) Pp[(size_t)o * NPIX + p] = acc[i][j];
        }
    }
}

// Sum split-K partials + bias (+ optional other-path add, optional relu)
__global__ void reduce_bias(
    const float* __restrict__ P, int Mpad, int nsplit,
    const float* __restrict__ bias, int M,
    const float* __restrict__ addbuf, int relu,
    float* __restrict__ out)
{
    int idx = blockIdx.x * blockDim.x + threadIdx.x;
    if (idx >= M * NPIX) return;
    int o = idx / NPIX;
    int p = idx - o * NPIX;
    float s = bias[o];
    for (int sp = 0; sp < nsplit; ++sp)
        s += P[((size_t)sp * Mpad + o) * NPIX + p];
    if (addbuf) s += addbuf[idx];
    if (relu) s = fmaxf(s, 0.f);
    out[idx] = s;
}

// ---------------------------------------------------------------------------
// PSROI bilinear pooling: per (roi, k) with k = (bin_i*7+bin_j)*10 + d,
// feature channel in h is exactly k. 2x2 sample points per bin, max-pool.
// ---------------------------------------------------------------------------
__global__ __launch_bounds__(512) void pool_kernel(
    const float* __restrict__ h, const float* __restrict__ rois,
    float* __restrict__ pooled)
{
    int n = blockIdx.x;
    int k = threadIdx.x;
    if (k >= 490) return;
    float x1 = rois[n * 4 + 0], y1 = rois[n * 4 + 1];
    float x2 = rois[n * 4 + 2], y2 = rois[n * 4 + 3];
    float xmin = x1 * (1.f / 16.f) / 50.f;
    float ymin = y1 * (1.f / 16.f) / 38.f;
    float xmax = x2 * (1.f / 16.f) / 50.f;
    float ymax = y2 * (1.f / 16.f) / 38.f;
    float step_x = (xmax - xmin) / 7.f;
    float step_y = (ymax - ymin) / 7.f;
    int bin = k / 10;
    int bi = bin / 7, bj = bin - bi * 7;
    const float* ch = h + (size_t)k * NPIX;
    float m = -INFINITY;
#pragma unroll
    for (int sy = 0; sy < 2; ++sy) {
        float yv = (ymin + (float)(bi + sy) * step_y) * 37.f;
        float y0 = floorf(yv);
        float fy = yv - y0;
        int yi0 = min(max((int)y0, 0), 37);
        int yi1 = min(max((int)y0 + 1, 0), 37);
#pragma unroll
        for (int sx = 0; sx < 2; ++sx) {
            float xv = (xmin + (float)(bj + sx) * step_x) * 49.f;
            float x0 = floorf(xv);
            float fx = xv - x0;
            int xi0 = min(max((int)x0, 0), 49);
            int xi1 = min(max((int)x0 + 1, 0), 49);
            float v00 = ch[yi0 * FW + xi0], v01 = ch[yi0 * FW + xi1];
            float v10 = ch[yi1 * FW + xi0], v11 = ch[yi1 * FW + xi1];
            float top = v00 + (v01 - v00) * fx;
            float bot = v10 + (v11 - v10) * fx;
            float val = top + (bot - top) * fy;
            m = fmaxf(m, val);
        }
    }
    pooled[(size_t)n * 490 + k] = m;
}

// ---------------------------------------------------------------------------
// NT GEMM: C[n,m] = (relu)(sum_k A[n*K+k]*B[m*K+k] + bias[m]), both K-contig.
// ---------------------------------------------------------------------------
__global__ __launch_bounds__(256) void fc_gemm(
    const float* __restrict__ A, const float* __restrict__ B,
    const float* __restrict__ bias, float* __restrict__ C,
    int Nr, int M, int K, int ldc, int relu)
{
    const int tx = threadIdx.x, ty = threadIdx.y;
    const int tid = ty * 16 + tx;
    const int nbase = blockIdx.y * 64;
    const int mbase = blockIdx.x * 64;
    __shared__ float As[64][17];
    __shared__ float Bs[64][17];
    const int rr = tid >> 2;
    const int kq = (tid & 3) << 2;

    float acc[4][4];
#pragma unroll
    for (int i = 0; i < 4; ++i)
#pragma unroll
        for (int j = 0; j < 4; ++j) acc[i][j] = 0.f;

    for (int kt = 0; kt < K; kt += 16) {
#pragma unroll
        for (int i = 0; i < 4; ++i) {
            int kg = kt + kq + i;
            As[rr][kq + i] = (nbase + rr < Nr && kg < K)
                               ? A[(size_t)(nbase + rr) * K + kg] : 0.f;
            Bs[rr][kq + i] = (mbase + rr < M && kg < K)
                               ? B[(size_t)(mbase + rr) * K + kg] : 0.f;
        }
        __syncthreads();
#pragma unroll
        for (int kk = 0; kk < 16; ++kk) {
            float a[4], b[4];
#pragma unroll
            for (int i = 0; i < 4; ++i) a[i] = As[ty * 4 + i][kk];
#pragma unroll
            for (int j = 0; j < 4; ++j) b[j] = Bs[tx * 4 + j][kk];
#pragma unroll
            for (int i = 0; i < 4; ++i)
#pragma unroll
                for (int j = 0; j < 4; ++j) acc[i][j] += a[i] * b[j];
        }
        __syncthreads();
    }
#pragma unroll
    for (int i = 0; i < 4; ++i) {
        int n = nbase + ty * 4 + i;
#pragma unroll
        for (int j = 0; j < 4; ++j) {
            int m = mbase + tx * 4 + j;
            if (n < Nr && m < M) {
                float v = acc[i][j] + bias[m];
                if (relu) v = fmaxf(v, 0.f);
                C[(size_t)n * ldc + m] = v;
            }
        }
    }
}

extern "C" void kernel_launch(void* const* d_in, const int* in_sizes, int n_in,
                              void* d_out, int out_size, void* d_ws, size_t ws_size,
                              hipStream_t stream) {
    const float* x         = (const float*)d_in[0];
    const float* rois      = (const float*)d_in[1];
    const float* w_col_max = (const float*)d_in[2];
    const float* b_col_max = (const float*)d_in[3];
    const float* w_col     = (const float*)d_in[4];
    const float* b_col     = (const float*)d_in[5];
    const float* w_row_max = (const float*)d_in[6];
    const float* b_row_max = (const float*)d_in[7];
    const float* w_row     = (const float*)d_in[8];
    const float* b_row     = (const float*)d_in[9];
    const float* w_fc1     = (const float*)d_in[10];
    const float* b_fc1     = (const float*)d_in[11];
    const float* w_score   = (const float*)d_in[12];
    const float* b_score   = (const float*)d_in[13];
    const float* w_loc     = (const float*)d_in[14];
    const float* b_loc     = (const float*)d_in[15];

    float* ws = (float*)d_ws;
    float* part   = ws;                    // max(8*256, 4*512)*1900 = 3,891,200
    float* c1col  = part + 3891200;        // 256*1900
    float* c1row  = c1col + 486400;        // 256*1900
    float* hcol   = c1row + 486400;        // 490*1900
    float* h      = hcol + 931000;         // 490*1900
    float* pooled = h + 931000;            // 512*490
    float* fc1    = pooled + 250880;       // 512*2048
    // total ~32.1 MB of workspace

    dim3 blk(16, 16);

    // conv1 col: 15x1 vertical, 2048->256, split-K 8
    conv_gemm<<<dim3(30, 4, 8), blk, 0, stream>>>(w_col_max, x, part, 256, 2048, 256, 1);
    reduce_bias<<<1900, 256, 0, stream>>>(part, 256, 8, b_col_max, 256, nullptr, 0, c1col);
    // conv1 row: 1x15 horizontal, 2048->256
    conv_gemm<<<dim3(30, 4, 8), blk, 0, stream>>>(w_row_max, x, part, 256, 2048, 256, 0);
    reduce_bias<<<1900, 256, 0, stream>>>(part, 256, 8, b_row_max, 256, nullptr, 0, c1row);
    // conv2 col: 1x15 horizontal, 256->490, split-K 4
    conv_gemm<<<dim3(30, 8, 4), blk, 0, stream>>>(w_col, c1col, part, 490, 256, 512, 0);
    reduce_bias<<<3637, 256, 0, stream>>>(part, 512, 4, b_col, 490, nullptr, 0, hcol);
    // conv2 row: 15x1 vertical, 256->490; fuse h = relu(hcol + this + b_row)
    conv_gemm<<<dim3(30, 8, 4), blk, 0, stream>>>(w_row, c1row, part, 490, 256, 512, 1);
    reduce_bias<<<3637, 256, 0, stream>>>(part, 512, 4, b_row, 490, hcol, 1, h);

    // PSROI pooling: one block per roi
    pool_kernel<<<512, 512, 0, stream>>>(h, rois, pooled);

    // fc1: (512x490)@(2048x490)^T, relu
    fc_gemm<<<dim3(32, 8), blk, 0, stream>>>(pooled, w_fc1, b_fc1, fc1, 512, 2048, 490, 2048, 1);
    float* out = (float*)d_out;
    // roi_cls_locs: (512x324)
    fc_gemm<<<dim3(6, 8), blk, 0, stream>>>(fc1, w_loc, b_loc, out, 512, 324, 2048, 324, 0);
    // roi_scores: (512x81), after locs in d_out
    fc_gemm<<<dim3(2, 8), blk, 0, stream>>>(fc1, w_score, b_score, out + 512 * 324, 512, 81, 2048, 81, 0);
}

// Round 2
// 1329.906 us; speedup vs baseline: 1.7544x; 1.7544x over previous
//
#include <hip/hip_runtime.h>
#include <math.h>

#define FH 38
#define FW 50
#define NPIX 1900   // 38*50
#define NROIS 512

typedef __bf16 bf16x8 __attribute__((ext_vector_type(8)));
typedef float  f32x4  __attribute__((ext_vector_type(4)));

__device__ __forceinline__ unsigned short f2b(float f) {
    unsigned int u = __float_as_uint(f);
    unsigned int r = (u + 0x7fffu + ((u >> 16) & 1u)) >> 16;   // RNE
    return (unsigned short)r;
}

// fp32 -> bf16 conversion, 4 elems/thread
__global__ __launch_bounds__(256) void cvt_bf16(
    const float* __restrict__ in, unsigned short* __restrict__ out, int n)
{
    int i = (blockIdx.x * 256 + threadIdx.x) * 4;
    if (i >= n) return;
    float4 v = *(const float4*)(in + i);
    ushort2 a, b;
    a.x = f2b(v.x); a.y = f2b(v.y);
    b.x = f2b(v.z); b.y = f2b(v.w);
    *(ushort2*)(out + i)     = a;
    *(ushort2*)(out + i + 2) = b;
}

// ---------------------------------------------------------------------------
// bf16 MFMA conv-as-GEMM with on-the-fly im2col, split-K fp32 partials.
//   C[o,p] = sum_k W[o][k] * X[c(k)][shift(p, r(k))],  k = c*15 + r
// Block: 256 thr = 4 waves; tile M=64 x N=64(pixels); K-step 32.
// Wave w: 32x32 subtile (mh = (w>>1)*32, nh = (w&1)*32) via 2x2 16x16x32 MFMAs.
// LDS: As[m][k] and Bt[p][k], row stride 40 ush (16B-aligned b128 access).
// ---------------------------------------------------------------------------
__global__ __launch_bounds__(256) void conv_mfma(
    const unsigned short* __restrict__ Wb,   // [M][K] bf16
    const unsigned short* __restrict__ Xb,   // [Kc][1900] bf16
    float* __restrict__ P, int M, int Kc, int Mpad, int vertical)
{
    const int K  = Kc * 15;
    const int Ks = K / gridDim.z;
    const int k0 = blockIdx.z * Ks;
    const int tid  = threadIdx.x;
    const int lane = tid & 63;
    const int wave = tid >> 6;
    const int obase = blockIdx.y * 64;
    const int pbase = blockIdx.x * 64;

    __shared__ unsigned short As[64][40];
    __shared__ unsigned short Bt[64][40];

    // A staging: 64 rows x 32 k; thread: m=tid>>2, k8=(tid&3)*8 -> one 16B ld/st
    const int a_m  = tid >> 2;
    const int a_k8 = (tid & 3) << 3;
    const int a_row = obase + a_m;
    const bool a_ok = a_row < M;
    const unsigned short* Aptr = Wb + (size_t)a_row * K + k0 + a_k8;

    // B staging: 64 pixels x 32 k; thread: pb=tid>>2, k8=(tid&3)*8
    const int b_pb = tid >> 2;
    const int b_k8 = (tid & 3) << 3;
    const int bp   = pbase + b_pb;
    const bool pok = bp < NPIX;
    const int py = bp / FW;
    const int px = bp - py * FW;

    f32x4 acc[2][2];
#pragma unroll
    for (int i = 0; i < 2; ++i)
#pragma unroll
        for (int j = 0; j < 2; ++j)
#pragma unroll
            for (int r = 0; r < 4; ++r) acc[i][j][r] = 0.f;

    const int mh = (wave >> 1) * 32;
    const int nh = (wave & 1) * 32;
    const int lm = lane & 15;
    const int l8 = (lane >> 4) * 8;

    for (int kt = k0; kt < k0 + Ks; kt += 32) {
        // ---- A tile ----
        if (a_ok) {
            *(uint4*)&As[a_m][a_k8] = *(const uint4*)Aptr;
        } else {
            uint4 z; z.x = z.y = z.z = z.w = 0u;
            *(uint4*)&As[a_m][a_k8] = z;
        }
        Aptr += 32;

        // ---- B tile (im2col gather: 8 consecutive k for one pixel) ----
        {
            int kg = kt + b_k8;
            int c  = kg / 15;
            int r  = kg - c * 15;
            const unsigned short* Xc = Xb + (size_t)c * NPIX;
            unsigned short tmp[8];
#pragma unroll
            for (int i = 0; i < 8; ++i) {
                unsigned short v = 0;
                if (pok) {
                    if (vertical) {
                        int yy = py + r - 7;
                        if (yy >= 0 && yy < FH) v = Xc[yy * FW + px];
                    } else {
                        int xx = px + r - 7;
                        if (xx >= 0 && xx < FW) v = Xc[py * FW + xx];
                    }
                }
                tmp[i] = v;
                if (++r == 15) { r = 0; Xc += NPIX; }
            }
            uint4 bw;
            bw.x = (unsigned)tmp[0] | ((unsigned)tmp[1] << 16);
            bw.y = (unsigned)tmp[2] | ((unsigned)tmp[3] << 16);
            bw.z = (unsigned)tmp[4] | ((unsigned)tmp[5] << 16);
            bw.w = (unsigned)tmp[6] | ((unsigned)tmp[7] << 16);
            *(uint4*)&Bt[b_pb][b_k8] = bw;
        }
        __syncthreads();

        bf16x8 a0 = __builtin_bit_cast(bf16x8, *(const uint4*)&As[mh + lm][l8]);
        bf16x8 a1 = __builtin_bit_cast(bf16x8, *(const uint4*)&As[mh + 16 + lm][l8]);
        bf16x8 b0 = __builtin_bit_cast(bf16x8, *(const uint4*)&Bt[nh + lm][l8]);
        bf16x8 b1 = __builtin_bit_cast(bf16x8, *(const uint4*)&Bt[nh + 16 + lm][l8]);

        acc[0][0] = __builtin_amdgcn_mfma_f32_16x16x32_bf16(a0, b0, acc[0][0], 0, 0, 0);
        acc[0][1] = __builtin_amdgcn_mfma_f32_16x16x32_bf16(a0, b1, acc[0][1], 0, 0, 0);
        acc[1][0] = __builtin_amdgcn_mfma_f32_16x16x32_bf16(a1, b0, acc[1][0], 0, 0, 0);
        acc[1][1] = __builtin_amdgcn_mfma_f32_16x16x32_bf16(a1, b1, acc[1][1], 0, 0, 0);
        __syncthreads();
    }

    float* Pp = P + (size_t)blockIdx.z * Mpad * NPIX;
#pragma unroll
    for (int ms = 0; ms < 2; ++ms)
#pragma unroll
        for (int ns = 0; ns < 2; ++ns) {
            int p = pbase + nh + ns * 16 + lm;
            if (p < NPIX) {
                int m0 = obase + mh + ms * 16 + (lane >> 4) * 4;
#pragma unroll
                for (int r = 0; r < 4; ++r)
                    Pp[(size_t)(m0 + r) * NPIX + p] = acc[ms][ns][r];
            }
        }
}

// Sum split-K partials + bias (+ optional add, relu); fp32 and/or bf16 out
__global__ void reduce_bias(
    const float* __restrict__ P, int Mpad, int nsplit,
    const float* __restrict__ bias, int M,
    const float* __restrict__ addbuf, int relu,
    float* __restrict__ outf, unsigned short* __restrict__ outb)
{
    int idx = blockIdx.x * blockDim.x + threadIdx.x;
    if (idx >= M * NPIX) return;
    int o = idx / NPIX;
    int p = idx - o * NPIX;
    float s = bias[o];
    for (int sp = 0; sp < nsplit; ++sp)
        s += P[((size_t)sp * Mpad + o) * NPIX + p];
    if (addbuf) s += addbuf[idx];
    if (relu) s = fmaxf(s, 0.f);
    if (outf) outf[idx] = s;
    if (outb) outb[idx] = f2b(s);
}

// ---------------------------------------------------------------------------
// PSROI bilinear pooling (fp32 h), unchanged from R1 (correct).
// ---------------------------------------------------------------------------
__global__ __launch_bounds__(512) void pool_kernel(
    const float* __restrict__ h, const float* __restrict__ rois,
    float* __restrict__ pooled)
{
    int n = blockIdx.x;
    int k = threadIdx.x;
    if (k >= 490) return;
    float x1 = rois[n * 4 + 0], y1 = rois[n * 4 + 1];
    float x2 = rois[n * 4 + 2], y2 = rois[n * 4 + 3];
    float xmin = x1 * (1.f / 16.f) / 50.f;
    float ymin = y1 * (1.f / 16.f) / 38.f;
    float xmax = x2 * (1.f / 16.f) / 50.f;
    float ymax = y2 * (1.f / 16.f) / 38.f;
    float step_x = (xmax - xmin) / 7.f;
    float step_y = (ymax - ymin) / 7.f;
    int bin = k / 10;
    int bi = bin / 7, bj = bin - bi * 7;
    const float* ch = h + (size_t)k * NPIX;
    float m = -INFINITY;
#pragma unroll
    for (int sy = 0; sy < 2; ++sy) {
        float yv = (ymin + (float)(bi + sy) * step_y) * 37.f;
        float y0 = floorf(yv);
        float fy = yv - y0;
        int yi0 = min(max((int)y0, 0), 37);
        int yi1 = min(max((int)y0 + 1, 0), 37);
#pragma unroll
        for (int sx = 0; sx < 2; ++sx) {
            float xv = (xmin + (float)(bj + sx) * step_x) * 49.f;
            float x0 = floorf(xv);
            float fx = xv - x0;
            int xi0 = min(max((int)x0, 0), 49);
            int xi1 = min(max((int)x0 + 1, 0), 49);
            float v00 = ch[yi0 * FW + xi0], v01 = ch[yi0 * FW + xi1];
            float v10 = ch[yi1 * FW + xi0], v11 = ch[yi1 * FW + xi1];
            float top = v00 + (v01 - v00) * fx;
            float bot = v10 + (v11 - v10) * fx;
            float val = top + (bot - top) * fy;
            m = fmaxf(m, val);
        }
    }
    pooled[(size_t)n * 490 + k] = m;
}

// ---------------------------------------------------------------------------
// NT GEMM fp32 (FC layers): C[n,m] = (relu)(A[n,:]·B[m,:] + bias[m])
// ---------------------------------------------------------------------------
__global__ __launch_bounds__(256) void fc_gemm(
    const float* __restrict__ A, const float* __restrict__ B,
    const float* __restrict__ bias, float* __restrict__ C,
    int Nr, int M, int K, int ldc, int relu)
{
    const int tx = threadIdx.x, ty = threadIdx.y;
    const int tid = ty * 16 + tx;
    const int nbase = blockIdx.y * 64;
    const int mbase = blockIdx.x * 64;
    __shared__ float As[64][17];
    __shared__ float Bs[64][17];
    const int rr = tid >> 2;
    const int kq = (tid & 3) << 2;

    float acc[4][4];
#pragma unroll
    for (int i = 0; i < 4; ++i)
#pragma unroll
        for (int j = 0; j < 4; ++j) acc[i][j] = 0.f;

    for (int kt = 0; kt < K; kt += 16) {
#pragma unroll
        for (int i = 0; i < 4; ++i) {
            int kg = kt + kq + i;
            As[rr][kq + i] = (nbase + rr < Nr && kg < K)
                               ? A[(size_t)(nbase + rr) * K + kg] : 0.f;
            Bs[rr][kq + i] = (mbase + rr < M && kg < K)
                               ? B[(size_t)(mbase + rr) * K + kg] : 0.f;
        }
        __syncthreads();
#pragma unroll
        for (int kk = 0; kk < 16; ++kk) {
            float a[4], b[4];
#pragma unroll
            for (int i = 0; i < 4; ++i) a[i] = As[ty * 4 + i][kk];
#pragma unroll
            for (int j = 0; j < 4; ++j) b[j] = Bs[tx * 4 + j][kk];
#pragma unroll
            for (int i = 0; i < 4; ++i)
#pragma unroll
                for (int j = 0; j < 4; ++j) acc[i][j] += a[i] * b[j];
        }
        __syncthreads();
    }
#pragma unroll
    for (int i = 0; i < 4; ++i) {
        int n = nbase + ty * 4 + i;
#pragma unroll
        for (int j = 0; j < 4; ++j) {
            int m = mbase + tx * 4 + j;
            if (n < Nr && m < M) {
                float v = acc[i][j] + bias[m];
                if (relu) v = fmaxf(v, 0.f);
                C[(size_t)n * ldc + m] = v;
            }
        }
    }
}

extern "C" void kernel_launch(void* const* d_in, const int* in_sizes, int n_in,
                              void* d_out, int out_size, void* d_ws, size_t ws_size,
                              hipStream_t stream) {
    const float* x         = (const float*)d_in[0];
    const float* rois      = (const float*)d_in[1];
    const float* w_col_max = (const float*)d_in[2];
    const float* b_col_max = (const float*)d_in[3];
    const float* w_col     = (const float*)d_in[4];
    const float* b_col     = (const float*)d_in[5];
    const float* w_row_max = (const float*)d_in[6];
    const float* b_row_max = (const float*)d_in[7];
    const float* w_row     = (const float*)d_in[8];
    const float* b_row     = (const float*)d_in[9];
    const float* w_fc1     = (const float*)d_in[10];
    const float* b_fc1     = (const float*)d_in[11];
    const float* w_score   = (const float*)d_in[12];
    const float* b_score   = (const float*)d_in[13];
    const float* w_loc     = (const float*)d_in[14];
    const float* b_loc     = (const float*)d_in[15];

    float* ws = (float*)d_ws;
    float* part   = ws;                          // 8*256*1900 = 3,891,200 f
    float* hcol   = part + 3891200;              //   931,000 f
    float* h      = hcol + 931000;               //   931,000 f
    float* pooled = h + 931000;                  //   250,880 f
    float* fc1    = pooled + 250880;             // 1,048,576 f
    unsigned short* xb     = (unsigned short*)(fc1 + 1048576);  // 3,891,200 us
    unsigned short* c1colb = xb + 3891200;       //   486,400 us
    unsigned short* c1rowb = c1colb + 486400;    //   486,400 us
    unsigned short* wcm    = c1rowb + 486400;    // 7,864,320 us
    unsigned short* wrm    = wcm + 7864320;      // 7,864,320 us
    unsigned short* wc     = wrm + 7864320;      // 1,881,600 us
    unsigned short* wr     = wc + 1881600;       // 1,881,600 us
    // total ~77 MB

    // bf16 conversions
    cvt_bf16<<<3800, 256, 0, stream>>>(x, xb, 3891200);
    cvt_bf16<<<7680, 256, 0, stream>>>(w_col_max, wcm, 7864320);
    cvt_bf16<<<7680, 256, 0, stream>>>(w_row_max, wrm, 7864320);
    cvt_bf16<<<1838, 256, 0, stream>>>(w_col, wc, 1881600);
    cvt_bf16<<<1838, 256, 0, stream>>>(w_row, wr, 1881600);

    // conv1 col: 15x1 vertical, 2048->256, split-K 8
    conv_mfma<<<dim3(30, 4, 8), 256, 0, stream>>>(wcm, xb, part, 256, 2048, 256, 1);
    reduce_bias<<<1900, 256, 0, stream>>>(part, 256, 8, b_col_max, 256, nullptr, 0, nullptr, c1colb);
    // conv1 row: 1x15 horizontal
    conv_mfma<<<dim3(30, 4, 8), 256, 0, stream>>>(wrm, xb, part, 256, 2048, 256, 0);
    reduce_bias<<<1900, 256, 0, stream>>>(part, 256, 8, b_row_max, 256, nullptr, 0, nullptr, c1rowb);
    // conv2 col: 1x15 horizontal, 256->490, split-K 2
    conv_mfma<<<dim3(30, 8, 2), 256, 0, stream>>>(wc, c1colb, part, 490, 256, 512, 0);
    reduce_bias<<<3637, 256, 0, stream>>>(part, 512, 2, b_col, 490, nullptr, 0, hcol, nullptr);
    // conv2 row: 15x1 vertical; fuse h = relu(hcol + this + b_row)
    conv_mfma<<<dim3(30, 8, 2), 256, 0, stream>>>(wr, c1rowb, part, 490, 256, 512, 1);
    reduce_bias<<<3637, 256, 0, stream>>>(part, 512, 2, b_row, 490, hcol, 1, h, nullptr);

    // PSROI pooling
    pool_kernel<<<512, 512, 0, stream>>>(h, rois, pooled);

    // FC layers (fp32)
    fc_gemm<<<dim3(32, 8), dim3(16, 16), 0, stream>>>(pooled, w_fc1, b_fc1, fc1, 512, 2048, 490, 2048, 1);
    float* out = (float*)d_out;
    fc_gemm<<<dim3(6, 8), dim3(16, 16), 0, stream>>>(fc1, w_loc, b_loc, out, 512, 324, 2048, 324, 0);
    fc_gemm<<<dim3(2, 8), dim3(16, 16), 0, stream>>>(fc1, w_score, b_score, out + 512 * 324, 512, 81, 2048, 81, 0);
}

// Round 3
// 712.117 us; speedup vs baseline: 3.2764x; 1.8675x over previous
//
#include <hip/hip_runtime.h>
#include <math.h>

#define FH 38
#define FW 50
#define NPIX 1900   // 38*50
#define NROIS 512

typedef __bf16 bf16x8 __attribute__((ext_vector_type(8)));
typedef float  f32x4  __attribute__((ext_vector_type(4)));

__device__ __forceinline__ unsigned short f2b(float f) {
    unsigned int u = __float_as_uint(f);
    unsigned int r = (u + 0x7fffu + ((u >> 16) & 1u)) >> 16;   // RNE
    return (unsigned short)r;
}

// fp32 -> bf16, 4 elems/thread, n % 4 == 0
__global__ __launch_bounds__(256) void cvt_bf16(
    const float* __restrict__ in, unsigned short* __restrict__ out, int n)
{
    int i = (blockIdx.x * 256 + threadIdx.x) * 4;
    if (i >= n) return;
    float4 v = *(const float4*)(in + i);
    ushort2 a, b;
    a.x = f2b(v.x); a.y = f2b(v.y);
    b.x = f2b(v.z); b.y = f2b(v.w);
    *(ushort2*)(out + i)     = a;
    *(ushort2*)(out + i + 2) = b;
}

// fp32 [rows][Kin] -> bf16 [rows][Kout] zero-padded
__global__ __launch_bounds__(256) void cvt_pad(
    const float* __restrict__ in, unsigned short* __restrict__ out,
    int rows, int Kin, int Kout)
{
    int idx = blockIdx.x * 256 + threadIdx.x;
    if (idx >= rows * Kout) return;
    int rw = idx / Kout, k = idx - rw * Kout;
    out[idx] = (k < Kin) ? f2b(in[(size_t)rw * Kin + k]) : (unsigned short)0;
}

// ---------------------------------------------------------------------------
// bf16 MFMA conv-as-GEMM with on-the-fly im2col, split-K fp32 partials.
// Software-pipelined: gather next K-tile into regs while MFMAing current.
// ---------------------------------------------------------------------------
__global__ __launch_bounds__(256) void conv_mfma(
    const unsigned short* __restrict__ Wb,   // [M][K] bf16
    const unsigned short* __restrict__ Xb,   // [Kc][1900] bf16
    float* __restrict__ P, int M, int Kc, int Mpad, int vertical)
{
    const int K  = Kc * 15;
    const int Ks = K / gridDim.z;
    const int k0 = blockIdx.z * Ks;
    const int tid  = threadIdx.x;
    const int lane = tid & 63;
    const int wave = tid >> 6;
    const int obase = blockIdx.y * 64;
    const int pbase = blockIdx.x * 64;

    __shared__ unsigned short As[64][40];
    __shared__ unsigned short Bt[64][40];

    const int a_m  = tid >> 2;
    const int a_k8 = (tid & 3) << 3;
    const int a_row = obase + a_m;
    const bool a_ok = a_row < M;
    const unsigned short* Abase = Wb + (size_t)a_row * K + a_k8;

    const int b_pb = tid >> 2;
    const int b_k8 = (tid & 3) << 3;
    const int bp   = pbase + b_pb;
    const bool pok = bp < NPIX;
    const int py = bp / FW;
    const int px = bp - py * FW;

    auto gatherA = [&](int kt) -> uint4 {
        if (a_ok) return *(const uint4*)(Abase + kt);
        uint4 z; z.x = z.y = z.z = z.w = 0u; return z;
    };
    auto gatherB = [&](int kt) -> uint4 {
        int kg = kt + b_k8;
        int c  = kg / 15;
        int r  = kg - c * 15;
        const unsigned short* Xc = Xb + (size_t)c * NPIX;
        unsigned short tmp[8];
#pragma unroll
        for (int i = 0; i < 8; ++i) {
            unsigned short v = 0;
            if (pok) {
                if (vertical) {
                    int yy = py + r - 7;
                    if (yy >= 0 && yy < FH) v = Xc[yy * FW + px];
                } else {
                    int xx = px + r - 7;
                    if (xx >= 0 && xx < FW) v = Xc[py * FW + xx];
                }
            }
            tmp[i] = v;
            if (++r == 15) { r = 0; Xc += NPIX; }
        }
        uint4 bw;
        bw.x = (unsigned)tmp[0] | ((unsigned)tmp[1] << 16);
        bw.y = (unsigned)tmp[2] | ((unsigned)tmp[3] << 16);
        bw.z = (unsigned)tmp[4] | ((unsigned)tmp[5] << 16);
        bw.w = (unsigned)tmp[6] | ((unsigned)tmp[7] << 16);
        return bw;
    };

    f32x4 acc[2][2];
#pragma unroll
    for (int i = 0; i < 2; ++i)
#pragma unroll
        for (int j = 0; j < 2; ++j)
#pragma unroll
            for (int r = 0; r < 4; ++r) acc[i][j][r] = 0.f;

    const int mh = (wave >> 1) * 32;
    const int nh = (wave & 1) * 32;
    const int lm = lane & 15;
    const int l8 = (lane >> 4) * 8;

    uint4 aReg = gatherA(k0);
    uint4 bReg = gatherB(k0);

    for (int kt = k0; kt < k0 + Ks; kt += 32) {
        *(uint4*)&As[a_m][a_k8] = aReg;
        *(uint4*)&Bt[b_pb][b_k8] = bReg;
        __syncthreads();

        if (kt + 32 < k0 + Ks) {      // prefetch next tile (overlaps MFMAs)
            aReg = gatherA(kt + 32);
            bReg = gatherB(kt + 32);
        }

        bf16x8 a0 = __builtin_bit_cast(bf16x8, *(const uint4*)&As[mh + lm][l8]);
        bf16x8 a1 = __builtin_bit_cast(bf16x8, *(const uint4*)&As[mh + 16 + lm][l8]);
        bf16x8 b0 = __builtin_bit_cast(bf16x8, *(const uint4*)&Bt[nh + lm][l8]);
        bf16x8 b1 = __builtin_bit_cast(bf16x8, *(const uint4*)&Bt[nh + 16 + lm][l8]);

        acc[0][0] = __builtin_amdgcn_mfma_f32_16x16x32_bf16(a0, b0, acc[0][0], 0, 0, 0);
        acc[0][1] = __builtin_amdgcn_mfma_f32_16x16x32_bf16(a0, b1, acc[0][1], 0, 0, 0);
        acc[1][0] = __builtin_amdgcn_mfma_f32_16x16x32_bf16(a1, b0, acc[1][0], 0, 0, 0);
        acc[1][1] = __builtin_amdgcn_mfma_f32_16x16x32_bf16(a1, b1, acc[1][1], 0, 0, 0);
        __syncthreads();
    }

    float* Pp = P + (size_t)blockIdx.z * Mpad * NPIX;
#pragma unroll
    for (int ms = 0; ms < 2; ++ms)
#pragma unroll
        for (int ns = 0; ns < 2; ++ns) {
            int p = pbase + nh + ns * 16 + lm;
            if (p < NPIX) {
                int m0 = obase + mh + ms * 16 + (lane >> 4) * 4;
#pragma unroll
                for (int r = 0; r < 4; ++r)
                    Pp[(size_t)(m0 + r) * NPIX + p] = acc[ms][ns][r];
            }
        }
}

// Sum conv split-K partials + bias (+ optional add, relu); fp32 and/or bf16 out
__global__ void reduce_bias(
    const float* __restrict__ P, int Mpad, int nsplit,
    const float* __restrict__ bias, int M,
    const float* __restrict__ addbuf, int relu,
    float* __restrict__ outf, unsigned short* __restrict__ outb)
{
    int idx = blockIdx.x * blockDim.x + threadIdx.x;
    if (idx >= M * NPIX) return;
    int o = idx / NPIX;
    int p = idx - o * NPIX;
    float s = bias[o];
    for (int sp = 0; sp < nsplit; ++sp)
        s += P[((size_t)sp * Mpad + o) * NPIX + p];
    if (addbuf) s += addbuf[idx];
    if (relu) s = fmaxf(s, 0.f);
    if (outf) outf[idx] = s;
    if (outb) outb[idx] = f2b(s);
}

// ---------------------------------------------------------------------------
// bf16 MFMA NT GEMM for FC layers. A = weights [M][Kld], B = acts [512][Kld],
// both bf16 K-contig, Kld % 32 == 0, rows 16B-aligned. Split-K via gridDim.z,
// fp32 partials P[split][512][Mpad]. Same fragment machinery as conv_mfma.
// ---------------------------------------------------------------------------
__global__ __launch_bounds__(256) void fc_mfma(
    const unsigned short* __restrict__ Wb,
    const unsigned short* __restrict__ Act,
    float* __restrict__ P, int M, int Kld, int Mpad)
{
    const int Ks = Kld / gridDim.z;
    const int k0 = blockIdx.z * Ks;
    const int tid  = threadIdx.x;
    const int lane = tid & 63;
    const int wave = tid >> 6;
    const int mbase = blockIdx.x * 64;   // weight rows
    const int nbase = blockIdx.y * 64;   // roi rows

    __shared__ unsigned short As[64][40];
    __shared__ unsigned short Bs[64][40];

    const int s_r  = tid >> 2;
    const int s_k8 = (tid & 3) << 3;
    const int a_row = mbase + s_r;
    const bool a_ok = a_row < M;
    const unsigned short* Abase = Wb + (size_t)a_row * Kld + s_k8;
    const unsigned short* Bbase = Act + (size_t)(nbase + s_r) * Kld + s_k8;

    f32x4 acc[2][2];
#pragma unroll
    for (int i = 0; i < 2; ++i)
#pragma unroll
        for (int j = 0; j < 2; ++j)
#pragma unroll
            for (int r = 0; r < 4; ++r) acc[i][j][r] = 0.f;

    const int mh = (wave >> 1) * 32;
    const int nh = (wave & 1) * 32;
    const int lm = lane & 15;
    const int l8 = (lane >> 4) * 8;

    uint4 aReg, bReg;
    {
        if (a_ok) aReg = *(const uint4*)(Abase + k0);
        else { aReg.x = aReg.y = aReg.z = aReg.w = 0u; }
        bReg = *(const uint4*)(Bbase + k0);
    }

    for (int kt = k0; kt < k0 + Ks; kt += 32) {
        *(uint4*)&As[s_r][s_k8] = aReg;
        *(uint4*)&Bs[s_r][s_k8] = bReg;
        __syncthreads();

        if (kt + 32 < k0 + Ks) {
            if (a_ok) aReg = *(const uint4*)(Abase + kt + 32);
            bReg = *(const uint4*)(Bbase + kt + 32);
        }

        bf16x8 a0 = __builtin_bit_cast(bf16x8, *(const uint4*)&As[mh + lm][l8]);
        bf16x8 a1 = __builtin_bit_cast(bf16x8, *(const uint4*)&As[mh + 16 + lm][l8]);
        bf16x8 b0 = __builtin_bit_cast(bf16x8, *(const uint4*)&Bs[nh + lm][l8]);
        bf16x8 b1 = __builtin_bit_cast(bf16x8, *(const uint4*)&Bs[nh + 16 + lm][l8]);

        acc[0][0] = __builtin_amdgcn_mfma_f32_16x16x32_bf16(a0, b0, acc[0][0], 0, 0, 0);
        acc[0][1] = __builtin_amdgcn_mfma_f32_16x16x32_bf16(a0, b1, acc[0][1], 0, 0, 0);
        acc[1][0] = __builtin_amdgcn_mfma_f32_16x16x32_bf16(a1, b0, acc[1][0], 0, 0, 0);
        acc[1][1] = __builtin_amdgcn_mfma_f32_16x16x32_bf16(a1, b1, acc[1][1], 0, 0, 0);
        __syncthreads();
    }

    // D[m=A row][n=B col]; store P[split][n][m], 4 consecutive m per lane
#pragma unroll
    for (int ms = 0; ms < 2; ++ms)
#pragma unroll
        for (int ns = 0; ns < 2; ++ns) {
            int n  = nbase + nh + ns * 16 + lm;
            int m0 = mbase + mh + ms * 16 + (lane >> 4) * 4;
            float* Pp = P + ((size_t)blockIdx.z * NROIS + n) * Mpad + m0;
            *(f32x4*)Pp = acc[ms][ns];
        }
}

// Sum fc split-K partials + bias, relu opt, fp32 and/or bf16 out
__global__ void fc_reduce(
    const float* __restrict__ P, int Mpad, int M, int nsplit,
    const float* __restrict__ bias, int relu,
    float* __restrict__ outf, unsigned short* __restrict__ outb)
{
    int idx = blockIdx.x * 256 + threadIdx.x;
    if (idx >= NROIS * M) return;
    int n = idx / M, m = idx - n * M;
    float s = bias[m];
    for (int sp = 0; sp < nsplit; ++sp)
        s += P[((size_t)sp * NROIS + n) * Mpad + m];
    if (relu) s = fmaxf(s, 0.f);
    if (outf) outf[idx] = s;
    if (outb) outb[idx] = f2b(s);
}

// ---------------------------------------------------------------------------
// PSROI bilinear pooling (fp32 h) -> bf16 pooled [512][512] zero-padded
// ---------------------------------------------------------------------------
__global__ __launch_bounds__(512) void pool_kernel(
    const float* __restrict__ h, const float* __restrict__ rois,
    unsigned short* __restrict__ pooledb)
{
    int n = blockIdx.x;
    int k = threadIdx.x;
    if (k >= 490) {
        pooledb[(size_t)n * 512 + k] = 0;
        return;
    }
    float x1 = rois[n * 4 + 0], y1 = rois[n * 4 + 1];
    float x2 = rois[n * 4 + 2], y2 = rois[n * 4 + 3];
    float xmin = x1 * (1.f / 16.f) / 50.f;
    float ymin = y1 * (1.f / 16.f) / 38.f;
    float xmax = x2 * (1.f / 16.f) / 50.f;
    float ymax = y2 * (1.f / 16.f) / 38.f;
    float step_x = (xmax - xmin) / 7.f;
    float step_y = (ymax - ymin) / 7.f;
    int bin = k / 10;
    int bi = bin / 7, bj = bin - bi * 7;
    const float* ch = h + (size_t)k * NPIX;
    float m = -INFINITY;
#pragma unroll
    for (int sy = 0; sy < 2; ++sy) {
        float yv = (ymin + (float)(bi + sy) * step_y) * 37.f;
        float y0 = floorf(yv);
        float fy = yv - y0;
        int yi0 = min(max((int)y0, 0), 37);
        int yi1 = min(max((int)y0 + 1, 0), 37);
#pragma unroll
        for (int sx = 0; sx < 2; ++sx) {
            float xv = (xmin + (float)(bj + sx) * step_x) * 49.f;
            float x0 = floorf(xv);
            float fx = xv - x0;
            int xi0 = min(max((int)x0, 0), 49);
            int xi1 = min(max((int)x0 + 1, 0), 49);
            float v00 = ch[yi0 * FW + xi0], v01 = ch[yi0 * FW + xi1];
            float v10 = ch[yi1 * FW + xi0], v11 = ch[yi1 * FW + xi1];
            float top = v00 + (v01 - v00) * fx;
            float bot = v10 + (v11 - v10) * fx;
            float val = top + (bot - top) * fy;
            m = fmaxf(m, val);
        }
    }
    pooledb[(size_t)n * 512 + k] = f2b(m);
}

extern "C" void kernel_launch(void* const* d_in, const int* in_sizes, int n_in,
                              void* d_out, int out_size, void* d_ws, size_t ws_size,
                              hipStream_t stream) {
    const float* x         = (const float*)d_in[0];
    const float* rois      = (const float*)d_in[1];
    const float* w_col_max = (const float*)d_in[2];
    const float* b_col_max = (const float*)d_in[3];
    const float* w_col     = (const float*)d_in[4];
    const float* b_col     = (const float*)d_in[5];
    const float* w_row_max = (const float*)d_in[6];
    const float* b_row_max = (const float*)d_in[7];
    const float* w_row     = (const float*)d_in[8];
    const float* b_row     = (const float*)d_in[9];
    const float* w_fc1     = (const float*)d_in[10];
    const float* b_fc1     = (const float*)d_in[11];
    const float* w_score   = (const float*)d_in[12];
    const float* b_score   = (const float*)d_in[13];
    const float* w_loc     = (const float*)d_in[14];
    const float* b_loc     = (const float*)d_in[15];

    float* ws = (float*)d_ws;
    float* part   = ws;                          // 3,891,200 f (conv partials; reused as fc partials)
    float* hcol   = part + 3891200;              //   931,000 f
    float* h      = hcol + 931000;               //   931,000 f
    unsigned short* xb      = (unsigned short*)(h + 931000);   // 3,891,200
    unsigned short* c1colb  = xb + 3891200;      //   486,400
    unsigned short* c1rowb  = c1colb + 486400;   //   486,400
    unsigned short* wcm     = c1rowb + 486400;   // 7,864,320
    unsigned short* wrm     = wcm + 7864320;     // 7,864,320
    unsigned short* wc      = wrm + 7864320;     // 1,881,600
    unsigned short* wr      = wc + 1881600;      // 1,881,600
    unsigned short* wfc1b   = wr + 1881600;      // 1,048,576  [2048][512]
    unsigned short* pooledb = wfc1b + 1048576;   //   262,144  [512][512]
    unsigned short* fc1b    = pooledb + 262144;  // 1,048,576  [512][2048]
    unsigned short* wlocb   = fc1b + 1048576;    //   663,552  [324][2048]
    unsigned short* wscoreb = wlocb + 663552;    //   165,888  [81][2048]
    // total ~78 MB

    // bf16 conversions
    cvt_bf16<<<3800, 256, 0, stream>>>(x, xb, 3891200);
    cvt_bf16<<<7680, 256, 0, stream>>>(w_col_max, wcm, 7864320);
    cvt_bf16<<<7680, 256, 0, stream>>>(w_row_max, wrm, 7864320);
    cvt_bf16<<<1838, 256, 0, stream>>>(w_col, wc, 1881600);
    cvt_bf16<<<1838, 256, 0, stream>>>(w_row, wr, 1881600);
    cvt_pad <<<4096, 256, 0, stream>>>(w_fc1, wfc1b, 2048, 490, 512);
    cvt_bf16<<<648,  256, 0, stream>>>(w_loc, wlocb, 663552);
    cvt_bf16<<<162,  256, 0, stream>>>(w_score, wscoreb, 165888);

    // conv1 col: 15x1 vertical, 2048->256, split-K 8
    conv_mfma<<<dim3(30, 4, 8), 256, 0, stream>>>(wcm, xb, part, 256, 2048, 256, 1);
    reduce_bias<<<1900, 256, 0, stream>>>(part, 256, 8, b_col_max, 256, nullptr, 0, nullptr, c1colb);
    // conv1 row: 1x15 horizontal
    conv_mfma<<<dim3(30, 4, 8), 256, 0, stream>>>(wrm, xb, part, 256, 2048, 256, 0);
    reduce_bias<<<1900, 256, 0, stream>>>(part, 256, 8, b_row_max, 256, nullptr, 0, nullptr, c1rowb);
    // conv2 col: 1x15 horizontal, 256->490, split-K 2
    conv_mfma<<<dim3(30, 8, 2), 256, 0, stream>>>(wc, c1colb, part, 490, 256, 512, 0);
    reduce_bias<<<3637, 256, 0, stream>>>(part, 512, 2, b_col, 490, nullptr, 0, hcol, nullptr);
    // conv2 row: 15x1 vertical; fuse h = relu(hcol + this + b_row)
    conv_mfma<<<dim3(30, 8, 2), 256, 0, stream>>>(wr, c1rowb, part, 490, 256, 512, 1);
    reduce_bias<<<3637, 256, 0, stream>>>(part, 512, 2, b_row, 490, hcol, 1, h, nullptr);

    // PSROI pooling -> bf16 padded [512][512]
    pool_kernel<<<512, 512, 0, stream>>>(h, rois, pooledb);

    float* out = (float*)d_out;
    // fc1: M=2048 feats, K=512 (padded 490), split 2 -> relu -> bf16 [512][2048]
    fc_mfma<<<dim3(32, 8, 2), 256, 0, stream>>>(wfc1b, pooledb, part, 2048, 512, 2048);
    fc_reduce<<<4096, 256, 0, stream>>>(part, 2048, 2048, 2, b_fc1, 1, nullptr, fc1b);
    // roi_cls_locs: M=324, K=2048, split 4
    fc_mfma<<<dim3(6, 8, 4), 256, 0, stream>>>(wlocb, fc1b, part, 324, 2048, 384);
    fc_reduce<<<648, 256, 0, stream>>>(part, 384, 324, 4, b_loc, 0, out, nullptr);
    // roi_scores: M=81, K=2048, split 8
    fc_mfma<<<dim3(2, 8, 8), 256, 0, stream>>>(wscoreb, fc1b, part, 81, 2048, 128);
    fc_reduce<<<162, 256, 0, stream>>>(part, 128, 81, 8, b_score, 0, out + 512 * 324, nullptr);
}

// Round 4
// 558.743 us; speedup vs baseline: 4.1757x; 1.2745x over previous
//
#include <hip/hip_runtime.h>
#include <math.h>

#define FW 50
#define FH 38
#define NPIX 1900   // 38*50
#define NROIS 512

// padded layouts
#define CSH 2470    // horizontal-consumed: [c][y*65 + x + t], width 65 = 50+15
#define CSV 2650    // vertical-consumed:   [c][x*53 + y + t], height 53 = 38+15

typedef __bf16 bf16x8 __attribute__((ext_vector_type(8)));
typedef float  f32x4  __attribute__((ext_vector_type(4)));

__device__ __forceinline__ unsigned short f2b(float f) {
    unsigned int u = __float_as_uint(f);
    unsigned int r = (u + 0x7fffu + ((u >> 16) & 1u)) >> 16;   // RNE
    return (unsigned short)r;
}

// ---------------- prep kernels ----------------

__global__ __launch_bounds__(256) void zero_us(unsigned short* __restrict__ p, int n) {
    int i = (blockIdx.x * 256 + threadIdx.x) * 8;
    if (i < n) { uint4 z; z.x = z.y = z.z = z.w = 0u; *(uint4*)(p + i) = z; }
}

// fp32 -> bf16, 4/thread
__global__ __launch_bounds__(256) void cvt_bf16(
    const float* __restrict__ in, unsigned short* __restrict__ out, int n)
{
    int i = (blockIdx.x * 256 + threadIdx.x) * 4;
    if (i >= n) return;
    float4 v = *(const float4*)(in + i);
    ushort2 a, b;
    a.x = f2b(v.x); a.y = f2b(v.y);
    b.x = f2b(v.z); b.y = f2b(v.w);
    *(ushort2*)(out + i)     = a;
    *(ushort2*)(out + i + 2) = b;
}

// fp32 [rows][Kin] -> bf16 [rows][Kout] zero-padded
__global__ __launch_bounds__(256) void cvt_pad(
    const float* __restrict__ in, unsigned short* __restrict__ out,
    int rows, int Kin, int Kout)
{
    int idx = blockIdx.x * 256 + threadIdx.x;
    if (idx >= rows * Kout) return;
    int rw = idx / Kout, k = idx - rw * Kout;
    out[idx] = (k < Kin) ? f2b(in[(size_t)rw * Kin + k]) : (unsigned short)0;
}

// weights fp32 [M][Kc][15] -> bf16 [M][Kc*16] (tap 15 = 0)
__global__ __launch_bounds__(256) void repack_w(
    const float* __restrict__ w, unsigned short* __restrict__ out, int n /* M*Kc*16 */)
{
    int idx = blockIdx.x * 256 + threadIdx.x;
    if (idx >= n) return;
    int t = idx & 15;
    int oc = idx >> 4;
    out[idx] = (t < 15) ? f2b(w[oc * 15 + t]) : (unsigned short)0;
}

// x fp32 [c][y][x] -> bf16 padded horizontal [c][y*65 + xc], xc = x+7
__global__ __launch_bounds__(256) void xpad_h(
    const float* __restrict__ xs, unsigned short* __restrict__ out)
{
    int idx = blockIdx.x * 256 + threadIdx.x;
    if (idx >= 2048 * CSH) return;
    int c = idx / CSH;
    int rem = idx - c * CSH;
    int y = rem / 65;
    int xc = rem - y * 65 - 7;
    unsigned short v = 0;
    if (xc >= 0 && xc < FW) v = f2b(xs[(c * FH + y) * FW + xc]);
    out[idx] = v;
}

// x fp32 [c][y][x] -> bf16 padded vertical (x-major) [c][x*53 + yc], yc = y+7
__global__ __launch_bounds__(256) void xpad_v(
    const float* __restrict__ xs, unsigned short* __restrict__ out)
{
    int idx = blockIdx.x * 256 + threadIdx.x;
    if (idx >= 2048 * CSV) return;
    int c = idx / CSV;
    int rem = idx - c * CSV;
    int xx = rem / 53;
    int yc = rem - xx * 53 - 7;
    unsigned short v = 0;
    if (yc >= 0 && yc < FH) v = f2b(xs[(c * FH + yc) * FW + xx]);
    out[idx] = v;
}

// ---------------------------------------------------------------------------
// Tap-padded bf16 MFMA conv-as-GEMM. K' = Kc*16 (16 taps/channel, tap15=0).
// B loads are contiguous dwords from the shift-padded input; alignbit fixes
// odd-element starts. Block tile 128(M)x128(pix), 4 waves 2x2, wave 64x64,
// BK=32 (2 channels x 16 taps). Split-K fp32 partials P[z][Mpad][1900].
// ---------------------------------------------------------------------------
__global__ __launch_bounds__(256) void conv_tap(
    const unsigned short* __restrict__ Wt,   // [M][Kp] bf16
    const unsigned short* __restrict__ Xp,   // [Kc][CS] padded bf16
    float* __restrict__ P,
    int M, int Kp, int Mpad, int CS, int yMul, int xMul)
{
    const int Ks = Kp / gridDim.z;
    const int k0 = blockIdx.z * Ks;
    const int tid  = threadIdx.x;
    const int lane = tid & 63;
    const int wave = tid >> 6;
    const int wy = (wave >> 1) * 64;
    const int wx = (wave & 1) * 64;
    const int mbase = blockIdx.y * 128;
    const int pbase = blockIdx.x * 128;

    __shared__ unsigned short As[128][40];
    __shared__ unsigned short Bt[128][40];

    const int rb   = tid >> 1;        // 0..127: A row / B pixel row
    const int half = tid & 1;         // which 16-k half (channel within pair)

    const int a_row = mbase + rb;
    const bool a_ok = a_row < M;
    const unsigned short* Abase = Wt + (size_t)a_row * Kp + half * 16;

    int p = pbase + rb;
    if (p > NPIX - 1) p = NPIX - 1;   // clamp: results discarded in epilogue
    const int py = p / FW, px = p - py * FW;
    const int pixBase = py * yMul + px * xMul;
    const unsigned sh = ((unsigned)pixBase & 1u) << 4;   // CS even -> parity fixed
    const unsigned* __restrict__ Bdw = (const unsigned*)Xp;

    f32x4 acc[4][4];
#pragma unroll
    for (int i = 0; i < 4; ++i)
#pragma unroll
        for (int j = 0; j < 4; ++j)
#pragma unroll
            for (int r = 0; r < 4; ++r) acc[i][j][r] = 0.f;

    const int lm = lane & 15;
    const int l8 = (lane >> 4) * 8;

    uint4 a0r, a1r;
    unsigned d[9];

    auto loadA = [&](int kt) {
        if (a_ok) {
            a0r = *(const uint4*)(Abase + kt);
            a1r = *(const uint4*)(Abase + kt + 8);
        } else {
            a0r.x = a0r.y = a0r.z = a0r.w = 0u;
            a1r = a0r;
        }
    };
    auto loadB = [&](int kt) {
        const int cg = (kt >> 4) + half;
        const unsigned base = ((unsigned)(cg * CS + pixBase)) >> 1;
#pragma unroll
        for (int j = 0; j < 9; ++j) d[j] = Bdw[base + j];
    };

    loadA(k0); loadB(k0);

    for (int kt = k0; kt < k0 + Ks; kt += 32) {
        unsigned ob[8];
#pragma unroll
        for (int j = 0; j < 8; ++j)
            ob[j] = __builtin_amdgcn_alignbit(d[j + 1], d[j], sh);
        *(uint4*)&As[rb][half * 16]     = a0r;
        *(uint4*)&As[rb][half * 16 + 8] = a1r;
        *(uint4*)&Bt[rb][half * 16]     = *(uint4*)&ob[0];
        *(uint4*)&Bt[rb][half * 16 + 8] = *(uint4*)&ob[4];
        __syncthreads();

        if (kt + 32 < k0 + Ks) { loadA(kt + 32); loadB(kt + 32); }

        bf16x8 af[4], bfr[4];
#pragma unroll
        for (int i = 0; i < 4; ++i)
            af[i] = __builtin_bit_cast(bf16x8, *(const uint4*)&As[wy + i * 16 + lm][l8]);
#pragma unroll
        for (int j = 0; j < 4; ++j)
            bfr[j] = __builtin_bit_cast(bf16x8, *(const uint4*)&Bt[wx + j * 16 + lm][l8]);
#pragma unroll
        for (int i = 0; i < 4; ++i)
#pragma unroll
            for (int j = 0; j < 4; ++j)
                acc[i][j] = __builtin_amdgcn_mfma_f32_16x16x32_bf16(af[i], bfr[j], acc[i][j], 0, 0, 0);
        __syncthreads();
    }

    float* Pp = P + (size_t)blockIdx.z * Mpad * NPIX;
#pragma unroll
    for (int i = 0; i < 4; ++i) {
        const int m0 = mbase + wy + i * 16 + (lane >> 4) * 4;
#pragma unroll
        for (int j = 0; j < 4; ++j) {
            const int pp = pbase + wx + j * 16 + lm;
            if (pp < NPIX) {
#pragma unroll
                for (int r = 0; r < 4; ++r)
                    Pp[(size_t)(m0 + r) * NPIX + pp] = acc[i][j][r];
            }
        }
    }
}

// conv1 reduce: sum partials + bias -> bf16 into next conv's padded layout
__global__ void reduce_pad(
    const float* __restrict__ P, int Mpad, int nsplit,
    const float* __restrict__ bias, int M,
    unsigned short* __restrict__ outb, int CS, int yMul, int xMul)
{
    int idx = blockIdx.x * 256 + threadIdx.x;
    if (idx >= M * NPIX) return;
    int o = idx / NPIX;
    int p = idx - o * NPIX;
    float s = bias[o];
    for (int sp = 0; sp < nsplit; ++sp)
        s += P[((size_t)sp * Mpad + o) * NPIX + p];
    int y = p / FW, x = p - y * FW;
    outb[(size_t)o * CS + y * yMul + x * xMul + 7] = f2b(s);
}

// conv2 reduce: sum partials + bias (+add, relu) -> fp32 raster
__global__ void reduce_bias(
    const float* __restrict__ P, int Mpad, int nsplit,
    const float* __restrict__ bias, int M,
    const float* __restrict__ addbuf, int relu,
    float* __restrict__ outf)
{
    int idx = blockIdx.x * blockDim.x + threadIdx.x;
    if (idx >= M * NPIX) return;
    int o = idx / NPIX;
    int p = idx - o * NPIX;
    float s = bias[o];
    for (int sp = 0; sp < nsplit; ++sp)
        s += P[((size_t)sp * Mpad + o) * NPIX + p];
    if (addbuf) s += addbuf[idx];
    if (relu) s = fmaxf(s, 0.f);
    outf[idx] = s;
}

// ---------------------------------------------------------------------------
// PSROI bilinear pooling (fp32 h) -> bf16 pooled [512][512] zero-padded
// ---------------------------------------------------------------------------
__global__ __launch_bounds__(512) void pool_kernel(
    const float* __restrict__ h, const float* __restrict__ rois,
    unsigned short* __restrict__ pooledb)
{
    int n = blockIdx.x;
    int k = threadIdx.x;
    if (k >= 490) {
        pooledb[(size_t)n * 512 + k] = 0;
        return;
    }
    float x1 = rois[n * 4 + 0], y1 = rois[n * 4 + 1];
    float x2 = rois[n * 4 + 2], y2 = rois[n * 4 + 3];
    float xmin = x1 * (1.f / 16.f) / 50.f;
    float ymin = y1 * (1.f / 16.f) / 38.f;
    float xmax = x2 * (1.f / 16.f) / 50.f;
    float ymax = y2 * (1.f / 16.f) / 38.f;
    float step_x = (xmax - xmin) / 7.f;
    float step_y = (ymax - ymin) / 7.f;
    int bin = k / 10;
    int bi = bin / 7, bj = bin - bi * 7;
    const float* ch = h + (size_t)k * NPIX;
    float m = -INFINITY;
#pragma unroll
    for (int sy = 0; sy < 2; ++sy) {
        float yv = (ymin + (float)(bi + sy) * step_y) * 37.f;
        float y0 = floorf(yv);
        float fy = yv - y0;
        int yi0 = min(max((int)y0, 0), 37);
        int yi1 = min(max((int)y0 + 1, 0), 37);
#pragma unroll
        for (int sx = 0; sx < 2; ++sx) {
            float xv = (xmin + (float)(bj + sx) * step_x) * 49.f;
            float x0 = floorf(xv);
            float fx = xv - x0;
            int xi0 = min(max((int)x0, 0), 49);
            int xi1 = min(max((int)x0 + 1, 0), 49);
            float v00 = ch[yi0 * FW + xi0], v01 = ch[yi0 * FW + xi1];
            float v10 = ch[yi1 * FW + xi0], v11 = ch[yi1 * FW + xi1];
            float top = v00 + (v01 - v00) * fx;
            float bot = v10 + (v11 - v10) * fx;
            float val = top + (bot - top) * fy;
            m = fmaxf(m, val);
        }
    }
    pooledb[(size_t)n * 512 + k] = f2b(m);
}

// ---------------------------------------------------------------------------
// bf16 MFMA NT GEMM (FC): A = weights [M][Kld], B = acts [512][Kld], split-K.
// ---------------------------------------------------------------------------
__global__ __launch_bounds__(256) void fc_mfma(
    const unsigned short* __restrict__ Wb,
    const unsigned short* __restrict__ Act,
    float* __restrict__ P, int M, int Kld, int Mpad)
{
    const int Ks = Kld / gridDim.z;
    const int k0 = blockIdx.z * Ks;
    const int tid  = threadIdx.x;
    const int lane = tid & 63;
    const int wave = tid >> 6;
    const int mbase = blockIdx.x * 64;
    const int nbase = blockIdx.y * 64;

    __shared__ unsigned short As[64][40];
    __shared__ unsigned short Bs[64][40];

    const int s_r  = tid >> 2;
    const int s_k8 = (tid & 3) << 3;
    const int a_row = mbase + s_r;
    const bool a_ok = a_row < M;
    const unsigned short* Abase = Wb + (size_t)a_row * Kld + s_k8;
    const unsigned short* Bbase = Act + (size_t)(nbase + s_r) * Kld + s_k8;

    f32x4 acc[2][2];
#pragma unroll
    for (int i = 0; i < 2; ++i)
#pragma unroll
        for (int j = 0; j < 2; ++j)
#pragma unroll
            for (int r = 0; r < 4; ++r) acc[i][j][r] = 0.f;

    const int mh = (wave >> 1) * 32;
    const int nh = (wave & 1) * 32;
    const int lm = lane & 15;
    const int l8 = (lane >> 4) * 8;

    uint4 aReg, bReg;
    if (a_ok) aReg = *(const uint4*)(Abase + k0);
    else { aReg.x = aReg.y = aReg.z = aReg.w = 0u; }
    bReg = *(const uint4*)(Bbase + k0);

    for (int kt = k0; kt < k0 + Ks; kt += 32) {
        *(uint4*)&As[s_r][s_k8] = aReg;
        *(uint4*)&Bs[s_r][s_k8] = bReg;
        __syncthreads();

        if (kt + 32 < k0 + Ks) {
            if (a_ok) aReg = *(const uint4*)(Abase + kt + 32);
            bReg = *(const uint4*)(Bbase + kt + 32);
        }

        bf16x8 a0 = __builtin_bit_cast(bf16x8, *(const uint4*)&As[mh + lm][l8]);
        bf16x8 a1 = __builtin_bit_cast(bf16x8, *(const uint4*)&As[mh + 16 + lm][l8]);
        bf16x8 b0 = __builtin_bit_cast(bf16x8, *(const uint4*)&Bs[nh + lm][l8]);
        bf16x8 b1 = __builtin_bit_cast(bf16x8, *(const uint4*)&Bs[nh + 16 + lm][l8]);

        acc[0][0] = __builtin_amdgcn_mfma_f32_16x16x32_bf16(a0, b0, acc[0][0], 0, 0, 0);
        acc[0][1] = __builtin_amdgcn_mfma_f32_16x16x32_bf16(a0, b1, acc[0][1], 0, 0, 0);
        acc[1][0] = __builtin_amdgcn_mfma_f32_16x16x32_bf16(a1, b0, acc[1][0], 0, 0, 0);
        acc[1][1] = __builtin_amdgcn_mfma_f32_16x16x32_bf16(a1, b1, acc[1][1], 0, 0, 0);
        __syncthreads();
    }

#pragma unroll
    for (int ms = 0; ms < 2; ++ms)
#pragma unroll
        for (int ns = 0; ns < 2; ++ns) {
            int n  = nbase + nh + ns * 16 + lm;
            int m0 = mbase + mh + ms * 16 + (lane >> 4) * 4;
            float* Pp = P + ((size_t)blockIdx.z * NROIS + n) * Mpad + m0;
            *(f32x4*)Pp = acc[ms][ns];
        }
}

__global__ void fc_reduce(
    const float* __restrict__ P, int Mpad, int M, int nsplit,
    const float* __restrict__ bias, int relu,
    float* __restrict__ outf, unsigned short* __restrict__ outb)
{
    int idx = blockIdx.x * 256 + threadIdx.x;
    if (idx >= NROIS * M) return;
    int n = idx / M, m = idx - n * M;
    float s = bias[m];
    for (int sp = 0; sp < nsplit; ++sp)
        s += P[((size_t)sp * NROIS + n) * Mpad + m];
    if (relu) s = fmaxf(s, 0.f);
    if (outf) outf[idx] = s;
    if (outb) outb[idx] = f2b(s);
}

extern "C" void kernel_launch(void* const* d_in, const int* in_sizes, int n_in,
                              void* d_out, int out_size, void* d_ws, size_t ws_size,
                              hipStream_t stream) {
    const float* x         = (const float*)d_in[0];
    const float* rois      = (const float*)d_in[1];
    const float* w_col_max = (const float*)d_in[2];
    const float* b_col_max = (const float*)d_in[3];
    const float* w_col     = (const float*)d_in[4];
    const float* b_col     = (const float*)d_in[5];
    const float* w_row_max = (const float*)d_in[6];
    const float* b_row_max = (const float*)d_in[7];
    const float* w_row     = (const float*)d_in[8];
    const float* b_row     = (const float*)d_in[9];
    const float* w_fc1     = (const float*)d_in[10];
    const float* b_fc1     = (const float*)d_in[11];
    const float* w_score   = (const float*)d_in[12];
    const float* b_score   = (const float*)d_in[13];
    const float* w_loc     = (const float*)d_in[14];
    const float* b_loc     = (const float*)d_in[15];

    float* part = (float*)d_ws;                        // 7,782,400 f = 31.1MB
    unsigned short* XvU   = (unsigned short*)(part + 7782400); // 5,427,264
    unsigned short* XhU   = XvU + 5427264;             // 5,058,624
    unsigned short* wbig  = XhU + 5058624;             // 8,388,608 (col-max, then row-max)
    unsigned short* wc16  = wbig + 8388608;            // 2,007,040
    unsigned short* wr16  = wc16 + 2007040;            // 2,007,040
    unsigned short* c1colb= wr16 + 2007040;            //   632,384
    unsigned short* c1rowb= c1colb + 632384;           //   678,464
    unsigned short* wfc1b = c1rowb + 678464;           // 1,048,576
    unsigned short* pooledb = wfc1b + 1048576;         //   262,144
    unsigned short* fc1b  = pooledb + 262144;          // 1,048,576
    unsigned short* wlocb = fc1b + 1048576;            //   663,552
    unsigned short* wscoreb = wlocb + 663552;          //   165,888
    float* hcol = (float*)XvU;                         // alias (Xv dead by then)
    float* h    = (float*)XhU;                         // alias (Xh dead by then)
    // total ~86 MB

    // ---- prep ----
    xpad_v<<<21200, 256, 0, stream>>>(x, XvU);
    xpad_h<<<19760, 256, 0, stream>>>(x, XhU);
    zero_us<<<309, 256, 0, stream>>>(c1colb, 632384);
    zero_us<<<332, 256, 0, stream>>>(c1rowb, 678464);
    repack_w<<<32768, 256, 0, stream>>>(w_col_max, wbig, 8388608);
    repack_w<<<7840, 256, 0, stream>>>(w_col, wc16, 2007040);
    repack_w<<<7840, 256, 0, stream>>>(w_row, wr16, 2007040);
    cvt_pad <<<4096, 256, 0, stream>>>(w_fc1, wfc1b, 2048, 490, 512);
    cvt_bf16<<<648,  256, 0, stream>>>(w_loc, wlocb, 663552);
    cvt_bf16<<<162,  256, 0, stream>>>(w_score, wscoreb, 165888);

    // ---- conv1 col (vertical 15x1): x-major padded input ----
    conv_tap<<<dim3(15, 2, 16), 256, 0, stream>>>(wbig, XvU, part, 256, 32768, 256, CSV, 1, 53);
    reduce_pad<<<1900, 256, 0, stream>>>(part, 256, 16, b_col_max, 256, c1colb, CSH, 65, 1);
    // repack row-max weights into the same big buffer (stream-serialized)
    repack_w<<<32768, 256, 0, stream>>>(w_row_max, wbig, 8388608);
    // ---- conv1 row (horizontal 1x15) ----
    conv_tap<<<dim3(15, 2, 16), 256, 0, stream>>>(wbig, XhU, part, 256, 32768, 256, CSH, 65, 1);
    reduce_pad<<<1900, 256, 0, stream>>>(part, 256, 16, b_row_max, 256, c1rowb, CSV, 1, 53);

    // ---- conv2 col (horizontal 1x15 on c1colb) ----
    conv_tap<<<dim3(15, 4, 8), 256, 0, stream>>>(wc16, c1colb, part, 490, 4096, 512, CSH, 65, 1);
    reduce_bias<<<3637, 256, 0, stream>>>(part, 512, 8, b_col, 490, nullptr, 0, hcol);
    // ---- conv2 row (vertical 15x1 on c1rowb); h = relu(hcol + this) ----
    conv_tap<<<dim3(15, 4, 8), 256, 0, stream>>>(wr16, c1rowb, part, 490, 4096, 512, CSV, 1, 53);
    reduce_bias<<<3637, 256, 0, stream>>>(part, 512, 8, b_row, 490, hcol, 1, h);

    // ---- PSROI pooling ----
    pool_kernel<<<512, 512, 0, stream>>>(h, rois, pooledb);

    float* out = (float*)d_out;
    // fc1: M=2048, K=512, split 2, relu -> bf16
    fc_mfma<<<dim3(32, 8, 2), 256, 0, stream>>>(wfc1b, pooledb, part, 2048, 512, 2048);
    fc_reduce<<<4096, 256, 0, stream>>>(part, 2048, 2048, 2, b_fc1, 1, nullptr, fc1b);
    // roi_cls_locs: M=324, K=2048, split 4
    fc_mfma<<<dim3(6, 8, 4), 256, 0, stream>>>(wlocb, fc1b, part, 324, 2048, 384);
    fc_reduce<<<648, 256, 0, stream>>>(part, 384, 324, 4, b_loc, 0, out, nullptr);
    // roi_scores: M=81, K=2048, split 8
    fc_mfma<<<dim3(2, 8, 8), 256, 0, stream>>>(wscoreb, fc1b, part, 81, 2048, 128);
    fc_reduce<<<162, 256, 0, stream>>>(part, 128, 81, 8, b_score, 0, out + 512 * 324, nullptr);
}

// Round 5
// 493.302 us; speedup vs baseline: 4.7297x; 1.1327x over previous
//
#include <hip/hip_runtime.h>
#include <math.h>

#define FW 50
#define FH 38
#define NPIX 1900   // 38*50
#define NROIS 512

// padded layouts
#define CSH 2470    // horizontal-consumed: [c][y*65 + x + t], width 65 = 50+15
#define CSV 2650    // vertical-consumed:   [c][x*53 + y + t], height 53 = 38+15

typedef __bf16 bf16x8 __attribute__((ext_vector_type(8)));
typedef float  f32x4  __attribute__((ext_vector_type(4)));

__device__ __forceinline__ unsigned short f2b(float f) {
    unsigned int u = __float_as_uint(f);
    unsigned int r = (u + 0x7fffu + ((u >> 16) & 1u)) >> 16;   // RNE
    return (unsigned short)r;
}

// ---------------- prep kernels ----------------

__global__ __launch_bounds__(256) void zero_us(unsigned short* __restrict__ p, int n) {
    int i = (blockIdx.x * 256 + threadIdx.x) * 8;
    if (i < n) { uint4 z; z.x = z.y = z.z = z.w = 0u; *(uint4*)(p + i) = z; }
}

__global__ __launch_bounds__(256) void cvt_bf16(
    const float* __restrict__ in, unsigned short* __restrict__ out, int n)
{
    int i = (blockIdx.x * 256 + threadIdx.x) * 4;
    if (i >= n) return;
    float4 v = *(const float4*)(in + i);
    ushort2 a, b;
    a.x = f2b(v.x); a.y = f2b(v.y);
    b.x = f2b(v.z); b.y = f2b(v.w);
    *(ushort2*)(out + i)     = a;
    *(ushort2*)(out + i + 2) = b;
}

__global__ __launch_bounds__(256) void cvt_pad(
    const float* __restrict__ in, unsigned short* __restrict__ out,
    int rows, int Kin, int Kout)
{
    int idx = blockIdx.x * 256 + threadIdx.x;
    if (idx >= rows * Kout) return;
    int rw = idx / Kout, k = idx - rw * Kout;
    out[idx] = (k < Kin) ? f2b(in[(size_t)rw * Kin + k]) : (unsigned short)0;
}

// weights fp32 [M][Kc][15] -> bf16 [M][Kc*16] (tap 15 = 0)
__global__ __launch_bounds__(256) void repack_w(
    const float* __restrict__ w, unsigned short* __restrict__ out, int n)
{
    int idx = blockIdx.x * 256 + threadIdx.x;
    if (idx >= n) return;
    int t = idx & 15;
    int oc = idx >> 4;
    out[idx] = (t < 15) ? f2b(w[oc * 15 + t]) : (unsigned short)0;
}

// x fp32 [c][y][x] -> bf16 padded horizontal [c][y*65 + xc], xc = x+7
__global__ __launch_bounds__(256) void xpad_h(
    const float* __restrict__ xs, unsigned short* __restrict__ out)
{
    int idx = blockIdx.x * 256 + threadIdx.x;
    if (idx >= 2048 * CSH) return;
    int c = idx / CSH;
    int rem = idx - c * CSH;
    int y = rem / 65;
    int xc = rem - y * 65 - 7;
    unsigned short v = 0;
    if (xc >= 0 && xc < FW) v = f2b(xs[(c * FH + y) * FW + xc]);
    out[idx] = v;
}

// x fp32 [c][y][x] -> bf16 padded vertical (x-major) [c][x*53 + yc], yc = y+7
__global__ __launch_bounds__(256) void xpad_v(
    const float* __restrict__ xs, unsigned short* __restrict__ out)
{
    int idx = blockIdx.x * 256 + threadIdx.x;
    if (idx >= 2048 * CSV) return;
    int c = idx / CSV;
    int rem = idx - c * CSV;
    int xx = rem / 53;
    int yc = rem - xx * 53 - 7;
    unsigned short v = 0;
    if (yc >= 0 && yc < FH) v = f2b(xs[(c * FH + yc) * FW + xx]);
    out[idx] = v;
}

// ---------------------------------------------------------------------------
// Tap-padded bf16 MFMA conv-as-GEMM, occupancy-tuned.
// Block tile 64(M) x 64(pix), 4 waves 2x2, wave 32x32, BK=32.
// 1D grid, XCD-aware swizzle: id%8 == z%8 -> all pixel-tiles sharing a
// weight slice run on one XCD (weight slice stays in that XCD's L2).
//   w = id & 63;  xt = id >> 6;  y = w >> zShift;  z = w & (nsplit-1)
// ---------------------------------------------------------------------------
__global__ __launch_bounds__(256) void conv_tap(
    const unsigned short* __restrict__ Wt,   // [M][Kp] bf16 (tap-16 packed)
    const unsigned short* __restrict__ Xp,   // [Kc][CS] padded bf16
    float* __restrict__ P,
    int M, int Kp, int Mpad, int CS, int yMul, int xMul,
    int zShift, int nsplit)
{
    const int id = blockIdx.x;
    const int w  = id & 63;
    const int xt = id >> 6;
    const int yt = w >> zShift;
    const int zt = w & (nsplit - 1);

    const int Ks = Kp / nsplit;
    const int k0 = zt * Ks;
    const int tid  = threadIdx.x;
    const int lane = tid & 63;
    const int wave = tid >> 6;
    const int mbase = yt * 64;
    const int pbase = xt * 64;

    __shared__ unsigned short As[64][40];
    __shared__ unsigned short Bt[64][40];

    // A staging: 64 rows x 32 k; thread: row=tid>>2, k8=(tid&3)*8, one uint4
    const int a_row = tid >> 2;
    const int a_k8  = (tid & 3) << 3;
    const unsigned short* Abase = Wt + (size_t)(mbase + a_row) * Kp + a_k8;
    const bool a_ok = (mbase + a_row) < M;

    // B staging: 64 pixels x 32 k; thread: pixel=tid>>2, quarter=(tid&3) -> 8 ks
    const int b_pix = tid >> 2;
    const int q     = tid & 3;
    int p = pbase + b_pix;
    if (p > NPIX - 1) p = NPIX - 1;          // clamp (stores guarded)
    const int py = p / FW, px = p - py * FW;
    const int pixBase = py * yMul + px * xMul;
    const int eoff = pixBase + ((q & 1) << 3);   // ushort index offset within channel
    const unsigned* __restrict__ Bdw = (const unsigned*)Xp;

    f32x4 acc[2][2];
#pragma unroll
    for (int i = 0; i < 2; ++i)
#pragma unroll
        for (int j = 0; j < 2; ++j)
#pragma unroll
            for (int r = 0; r < 4; ++r) acc[i][j][r] = 0.f;

    const int wy = (wave >> 1) * 32;
    const int wx = (wave & 1) * 32;
    const int lm = lane & 15;
    const int l8 = (lane >> 4) * 8;

    uint4 aR;
    unsigned d[5];

    auto loadA = [&](int kt) {
        if (a_ok) aR = *(const uint4*)(Abase + kt);
        else { aR.x = aR.y = aR.z = aR.w = 0u; }
    };
    auto loadB = [&](int kt) {
        const int cg = (kt >> 4) + (q >> 1);           // channel for this quarter
        const int e  = cg * CS + eoff;                 // ushort index
        const unsigned base = ((unsigned)e) >> 1;
#pragma unroll
        for (int j = 0; j < 5; ++j) d[j] = Bdw[base + j];
    };

    loadA(k0); loadB(k0);
    const unsigned sh = ((unsigned)(pixBase & 1)) << 4;  // CS even -> parity fixed

    for (int kt = k0; kt < k0 + Ks; kt += 32) {
        unsigned ob[4];
#pragma unroll
        for (int j = 0; j < 4; ++j)
            ob[j] = __builtin_amdgcn_alignbit(d[j + 1], d[j], sh);
        *(uint4*)&As[a_row][a_k8] = aR;
        *(uint4*)&Bt[b_pix][q << 3] = *(uint4*)&ob[0];
        __syncthreads();

        if (kt + 32 < k0 + Ks) { loadA(kt + 32); loadB(kt + 32); }

        bf16x8 af[2], bfr[2];
#pragma unroll
        for (int i = 0; i < 2; ++i)
            af[i]  = __builtin_bit_cast(bf16x8, *(const uint4*)&As[wy + i * 16 + lm][l8]);
#pragma unroll
        for (int j = 0; j < 2; ++j)
            bfr[j] = __builtin_bit_cast(bf16x8, *(const uint4*)&Bt[wx + j * 16 + lm][l8]);
#pragma unroll
        for (int i = 0; i < 2; ++i)
#pragma unroll
            for (int j = 0; j < 2; ++j)
                acc[i][j] = __builtin_amdgcn_mfma_f32_16x16x32_bf16(af[i], bfr[j], acc[i][j], 0, 0, 0);
        __syncthreads();
    }

    float* Pp = P + (size_t)zt * Mpad * NPIX;
#pragma unroll
    for (int i = 0; i < 2; ++i) {
        const int m0 = mbase + wy + i * 16 + (lane >> 4) * 4;
#pragma unroll
        for (int j = 0; j < 2; ++j) {
            const int pp = pbase + wx + j * 16 + lm;
            if (pp < NPIX) {
#pragma unroll
                for (int r = 0; r < 4; ++r)
                    Pp[(size_t)(m0 + r) * NPIX + pp] = acc[i][j][r];
            }
        }
    }
}

// conv1 reduce: sum partials + bias -> bf16 into next conv's padded layout
__global__ void reduce_pad(
    const float* __restrict__ P, int Mpad, int nsplit,
    const float* __restrict__ bias, int M,
    unsigned short* __restrict__ outb, int CS, int yMul, int xMul)
{
    int idx = blockIdx.x * 256 + threadIdx.x;
    if (idx >= M * NPIX) return;
    int o = idx / NPIX;
    int p = idx - o * NPIX;
    float s = bias[o];
    for (int sp = 0; sp < nsplit; ++sp)
        s += P[((size_t)sp * Mpad + o) * NPIX + p];
    int y = p / FW, x = p - y * FW;
    outb[(size_t)o * CS + y * yMul + x * xMul + 7] = f2b(s);
}

// conv2 reduce: sum partials + bias (+add, relu) -> fp32 raster
__global__ void reduce_bias(
    const float* __restrict__ P, int Mpad, int nsplit,
    const float* __restrict__ bias, int M,
    const float* __restrict__ addbuf, int relu,
    float* __restrict__ outf)
{
    int idx = blockIdx.x * blockDim.x + threadIdx.x;
    if (idx >= M * NPIX) return;
    int o = idx / NPIX;
    int p = idx - o * NPIX;
    float s = bias[o];
    for (int sp = 0; sp < nsplit; ++sp)
        s += P[((size_t)sp * Mpad + o) * NPIX + p];
    if (addbuf) s += addbuf[idx];
    if (relu) s = fmaxf(s, 0.f);
    outf[idx] = s;
}

// ---------------------------------------------------------------------------
// PSROI bilinear pooling (fp32 h) -> bf16 pooled [512][512] zero-padded
// ---------------------------------------------------------------------------
__global__ __launch_bounds__(512) void pool_kernel(
    const float* __restrict__ h, const float* __restrict__ rois,
    unsigned short* __restrict__ pooledb)
{
    int n = blockIdx.x;
    int k = threadIdx.x;
    if (k >= 490) {
        pooledb[(size_t)n * 512 + k] = 0;
        return;
    }
    float x1 = rois[n * 4 + 0], y1 = rois[n * 4 + 1];
    float x2 = rois[n * 4 + 2], y2 = rois[n * 4 + 3];
    float xmin = x1 * (1.f / 16.f) / 50.f;
    float ymin = y1 * (1.f / 16.f) / 38.f;
    float xmax = x2 * (1.f / 16.f) / 50.f;
    float ymax = y2 * (1.f / 16.f) / 38.f;
    float step_x = (xmax - xmin) / 7.f;
    float step_y = (ymax - ymin) / 7.f;
    int bin = k / 10;
    int bi = bin / 7, bj = bin - bi * 7;
    const float* ch = h + (size_t)k * NPIX;
    float m = -INFINITY;
#pragma unroll
    for (int sy = 0; sy < 2; ++sy) {
        float yv = (ymin + (float)(bi + sy) * step_y) * 37.f;
        float y0 = floorf(yv);
        float fy = yv - y0;
        int yi0 = min(max((int)y0, 0), 37);
        int yi1 = min(max((int)y0 + 1, 0), 37);
#pragma unroll
        for (int sx = 0; sx < 2; ++sx) {
            float xv = (xmin + (float)(bj + sx) * step_x) * 49.f;
            float x0 = floorf(xv);
            float fx = xv - x0;
            int xi0 = min(max((int)x0, 0), 49);
            int xi1 = min(max((int)x0 + 1, 0), 49);
            float v00 = ch[yi0 * FW + xi0], v01 = ch[yi0 * FW + xi1];
            float v10 = ch[yi1 * FW + xi0], v11 = ch[yi1 * FW + xi1];
            float top = v00 + (v01 - v00) * fx;
            float bot = v10 + (v11 - v10) * fx;
            float val = top + (bot - top) * fy;
            m = fmaxf(m, val);
        }
    }
    pooledb[(size_t)n * 512 + k] = f2b(m);
}

// ---------------------------------------------------------------------------
// bf16 MFMA NT GEMM (FC): A = weights [M][Kld], B = acts [512][Kld], split-K.
// ---------------------------------------------------------------------------
__global__ __launch_bounds__(256) void fc_mfma(
    const unsigned short* __restrict__ Wb,
    const unsigned short* __restrict__ Act,
    float* __restrict__ P, int M, int Kld, int Mpad)
{
    const int Ks = Kld / gridDim.z;
    const int k0 = blockIdx.z * Ks;
    const int tid  = threadIdx.x;
    const int lane = tid & 63;
    const int wave = tid >> 6;
    const int mbase = blockIdx.x * 64;
    const int nbase = blockIdx.y * 64;

    __shared__ unsigned short As[64][40];
    __shared__ unsigned short Bs[64][40];

    const int s_r  = tid >> 2;
    const int s_k8 = (tid & 3) << 3;
    const int a_row = mbase + s_r;
    const bool a_ok = a_row < M;
    const unsigned short* Abase = Wb + (size_t)a_row * Kld + s_k8;
    const unsigned short* Bbase = Act + (size_t)(nbase + s_r) * Kld + s_k8;

    f32x4 acc[2][2];
#pragma unroll
    for (int i = 0; i < 2; ++i)
#pragma unroll
        for (int j = 0; j < 2; ++j)
#pragma unroll
            for (int r = 0; r < 4; ++r) acc[i][j][r] = 0.f;

    const int mh = (wave >> 1) * 32;
    const int nh = (wave & 1) * 32;
    const int lm = lane & 15;
    const int l8 = (lane >> 4) * 8;

    uint4 aReg, bReg;
    if (a_ok) aReg = *(const uint4*)(Abase + k0);
    else { aReg.x = aReg.y = aReg.z = aReg.w = 0u; }
    bReg = *(const uint4*)(Bbase + k0);

    for (int kt = k0; kt < k0 + Ks; kt += 32) {
        *(uint4*)&As[s_r][s_k8] = aReg;
        *(uint4*)&Bs[s_r][s_k8] = bReg;
        __syncthreads();

        if (kt + 32 < k0 + Ks) {
            if (a_ok) aReg = *(const uint4*)(Abase + kt + 32);
            bReg = *(const uint4*)(Bbase + kt + 32);
        }

        bf16x8 a0 = __builtin_bit_cast(bf16x8, *(const uint4*)&As[mh + lm][l8]);
        bf16x8 a1 = __builtin_bit_cast(bf16x8, *(const uint4*)&As[mh + 16 + lm][l8]);
        bf16x8 b0 = __builtin_bit_cast(bf16x8, *(const uint4*)&Bs[nh + lm][l8]);
        bf16x8 b1 = __builtin_bit_cast(bf16x8, *(const uint4*)&Bs[nh + 16 + lm][l8]);

        acc[0][0] = __builtin_amdgcn_mfma_f32_16x16x32_bf16(a0, b0, acc[0][0], 0, 0, 0);
        acc[0][1] = __builtin_amdgcn_mfma_f32_16x16x32_bf16(a0, b1, acc[0][1], 0, 0, 0);
        acc[1][0] = __builtin_amdgcn_mfma_f32_16x16x32_bf16(a1, b0, acc[1][0], 0, 0, 0);
        acc[1][1] = __builtin_amdgcn_mfma_f32_16x16x32_bf16(a1, b1, acc[1][1], 0, 0, 0);
        __syncthreads();
    }

#pragma unroll
    for (int ms = 0; ms < 2; ++ms)
#pragma unroll
        for (int ns = 0; ns < 2; ++ns) {
            int n  = nbase + nh + ns * 16 + lm;
            int m0 = mbase + mh + ms * 16 + (lane >> 4) * 4;
            float* Pp = P + ((size_t)blockIdx.z * NROIS + n) * Mpad + m0;
            *(f32x4*)Pp = acc[ms][ns];
        }
}

__global__ void fc_reduce(
    const float* __restrict__ P, int Mpad, int M, int nsplit,
    const float* __restrict__ bias, int relu,
    float* __restrict__ outf, unsigned short* __restrict__ outb)
{
    int idx = blockIdx.x * 256 + threadIdx.x;
    if (idx >= NROIS * M) return;
    int n = idx / M, m = idx - n * M;
    float s = bias[m];
    for (int sp = 0; sp < nsplit; ++sp)
        s += P[((size_t)sp * NROIS + n) * Mpad + m];
    if (relu) s = fmaxf(s, 0.f);
    if (outf) outf[idx] = s;
    if (outb) outb[idx] = f2b(s);
}

extern "C" void kernel_launch(void* const* d_in, const int* in_sizes, int n_in,
                              void* d_out, int out_size, void* d_ws, size_t ws_size,
                              hipStream_t stream) {
    const float* x         = (const float*)d_in[0];
    const float* rois      = (const float*)d_in[1];
    const float* w_col_max = (const float*)d_in[2];
    const float* b_col_max = (const float*)d_in[3];
    const float* w_col     = (const float*)d_in[4];
    const float* b_col     = (const float*)d_in[5];
    const float* w_row_max = (const float*)d_in[6];
    const float* b_row_max = (const float*)d_in[7];
    const float* w_row     = (const float*)d_in[8];
    const float* b_row     = (const float*)d_in[9];
    const float* w_fc1     = (const float*)d_in[10];
    const float* b_fc1     = (const float*)d_in[11];
    const float* w_score   = (const float*)d_in[12];
    const float* b_score   = (const float*)d_in[13];
    const float* w_loc     = (const float*)d_in[14];
    const float* b_loc     = (const float*)d_in[15];

    float* part = (float*)d_ws;                        // 7,782,400 f = 31.1MB
    unsigned short* XvU   = (unsigned short*)(part + 7782400); // 5,427,264
    unsigned short* XhU   = XvU + 5427264;             // 5,058,624
    unsigned short* wbig  = XhU + 5058624;             // 8,388,608 (col-max, then row-max)
    unsigned short* wc16  = wbig + 8388608;            // 2,007,040
    unsigned short* wr16  = wc16 + 2007040;            // 2,007,040
    unsigned short* c1colb= wr16 + 2007040;            //   632,384
    unsigned short* c1rowb= c1colb + 632384;           //   678,464
    unsigned short* wfc1b = c1rowb + 678464;           // 1,048,576
    unsigned short* pooledb = wfc1b + 1048576;         //   262,144
    unsigned short* fc1b  = pooledb + 262144;          // 1,048,576
    unsigned short* wlocb = fc1b + 1048576;            //   663,552
    unsigned short* wscoreb = wlocb + 663552;          //   165,888
    float* hcol = (float*)XvU;                         // alias (Xv dead by then)
    float* h    = (float*)XhU;                         // alias (Xh dead by then)
    // total ~86 MB

    // ---- prep ----
    xpad_v<<<21200, 256, 0, stream>>>(x, XvU);
    xpad_h<<<19760, 256, 0, stream>>>(x, XhU);
    zero_us<<<309, 256, 0, stream>>>(c1colb, 632384);
    zero_us<<<332, 256, 0, stream>>>(c1rowb, 678464);
    repack_w<<<32768, 256, 0, stream>>>(w_col_max, wbig, 8388608);
    repack_w<<<7840, 256, 0, stream>>>(w_col, wc16, 2007040);
    repack_w<<<7840, 256, 0, stream>>>(w_row, wr16, 2007040);
    cvt_pad <<<4096, 256, 0, stream>>>(w_fc1, wfc1b, 2048, 490, 512);
    cvt_bf16<<<648,  256, 0, stream>>>(w_loc, wlocb, 663552);
    cvt_bf16<<<162,  256, 0, stream>>>(w_score, wscoreb, 165888);

    // ---- conv1 col (vertical 15x1), M=256: 30x * 4y * 16z = 1920 blocks ----
    conv_tap<<<1920, 256, 0, stream>>>(wbig, XvU, part, 256, 32768, 256, CSV, 1, 53, 4, 16);
    reduce_pad<<<1900, 256, 0, stream>>>(part, 256, 16, b_col_max, 256, c1colb, CSH, 65, 1);
    repack_w<<<32768, 256, 0, stream>>>(w_row_max, wbig, 8388608);
    // ---- conv1 row (horizontal 1x15) ----
    conv_tap<<<1920, 256, 0, stream>>>(wbig, XhU, part, 256, 32768, 256, CSH, 65, 1, 4, 16);
    reduce_pad<<<1900, 256, 0, stream>>>(part, 256, 16, b_row_max, 256, c1rowb, CSV, 1, 53);

    // ---- conv2 col (horizontal 1x15), M=490 (Mpad 512): 30x * 8y * 8z ----
    conv_tap<<<1920, 256, 0, stream>>>(wc16, c1colb, part, 490, 4096, 512, CSH, 65, 1, 3, 8);
    reduce_bias<<<3637, 256, 0, stream>>>(part, 512, 8, b_col, 490, nullptr, 0, hcol);
    // ---- conv2 row (vertical 15x1); h = relu(hcol + this) ----
    conv_tap<<<1920, 256, 0, stream>>>(wr16, c1rowb, part, 490, 4096, 512, CSV, 1, 53, 3, 8);
    reduce_bias<<<3637, 256, 0, stream>>>(part, 512, 8, b_row, 490, hcol, 1, h);

    // ---- PSROI pooling ----
    pool_kernel<<<512, 512, 0, stream>>>(h, rois, pooledb);

    float* out = (float*)d_out;
    // fc1: M=2048, K=512, split 2, relu -> bf16
    fc_mfma<<<dim3(32, 8, 2), 256, 0, stream>>>(wfc1b, pooledb, part, 2048, 512, 2048);
    fc_reduce<<<4096, 256, 0, stream>>>(part, 2048, 2048, 2, b_fc1, 1, nullptr, fc1b);
    // roi_cls_locs: M=324, K=2048, split 4
    fc_mfma<<<dim3(6, 8, 4), 256, 0, stream>>>(wlocb, fc1b, part, 324, 2048, 384);
    fc_reduce<<<648, 256, 0, stream>>>(part, 384, 324, 4, b_loc, 0, out, nullptr);
    // roi_scores: M=81, K=2048, split 8
    fc_mfma<<<dim3(2, 8, 8), 256, 0, stream>>>(wscoreb, fc1b, part, 81, 2048, 128);
    fc_reduce<<<162, 256, 0, stream>>>(part, 128, 81, 8, b_score, 0, out + 512 * 324, nullptr);
}